// Round 4
// baseline (1157.764 us; speedup 1.0000x reference)
//
#include <hip/hip_runtime.h>
#include <cstdint>
#include <cstddef>

typedef unsigned short u16;
typedef __attribute__((ext_vector_type(8))) short bf16x8;   // 8 bf16 = 4 VGPRs
typedef __attribute__((ext_vector_type(4))) float f32x4;    // MFMA accumulator

#define DEVFN static __device__ __forceinline__

DEVFN u16 f2bf(float f) {
  unsigned u = __float_as_uint(f);
  unsigned r = (u + 0x7FFFu + ((u >> 16) & 1u)) >> 16;   // RTN-even
  return (u16)r;
}

// async global->LDS, 16B/lane. LDS dest = wave-uniform base + lane*16 (m104/m108).
DEVFN void gload16(const void* g, void* l) {
  __builtin_amdgcn_global_load_lds(
      (const __attribute__((address_space(1))) void*)g,
      (__attribute__((address_space(3))) void*)l, 16, 0, 0);
}

// ---------------- merged prep: converts + wqkv row-permute + cos/sin table ----------------
// wqkv q/k rows interleaved per head: d<64 -> 2d, d>=64 -> 2(d-64)+1  (QK^T invariant).
// cs[l*64+m] = (cos(l,m), sin(l,m))
__global__ void prep(const float* __restrict__ x, const float* __restrict__ wqkv,
                     const float* __restrict__ wout, const float* __restrict__ cosp,
                     const float* __restrict__ sinp, u16* __restrict__ xb,
                     u16* __restrict__ wqkvb, u16* __restrict__ woutb,
                     float2* __restrict__ cs) {
  constexpr int X4 = 4194304;      // x elems/4
  constexpr int W4 = 3145728;      // wqkv elems/4
  constexpr int O4 = 1048576;      // wout elems/4
  int i = blockIdx.x * blockDim.x + threadIdx.x;
  if (i < X4) {
    float4 v = ((const float4*)x)[i];
    unsigned long long w = (unsigned long long)f2bf(v.x)
        | ((unsigned long long)f2bf(v.y) << 16)
        | ((unsigned long long)f2bf(v.z) << 32)
        | ((unsigned long long)f2bf(v.w) << 48);
    *(unsigned long long*)(xb + (size_t)i * 4) = w;
  } else if (i < X4 + W4) {
    int j = i - X4;
    int base = j * 4;
    int e = base >> 11, col = base & 2047;
    int e2;
    if (e < 4096) {
      int part = e >> 11, loc = e & 2047;
      int h = loc >> 7, d = loc & 127;
      int d2 = (d < 64) ? 2 * d : 2 * (d - 64) + 1;
      e2 = part * 2048 + h * 128 + d2;
    } else {
      e2 = e;                      // v rows unpermuted
    }
    float4 v = *(const float4*)&wqkv[(size_t)base];
    unsigned long long w = (unsigned long long)f2bf(v.x)
        | ((unsigned long long)f2bf(v.y) << 16)
        | ((unsigned long long)f2bf(v.z) << 32)
        | ((unsigned long long)f2bf(v.w) << 48);
    *(unsigned long long*)(wqkvb + (size_t)e2 * 2048 + col) = w;
  } else if (i < X4 + W4 + O4) {
    int j = i - X4 - W4;
    float4 v = ((const float4*)wout)[j];
    unsigned long long w = (unsigned long long)f2bf(v.x)
        | ((unsigned long long)f2bf(v.y) << 16)
        | ((unsigned long long)f2bf(v.z) << 32)
        | ((unsigned long long)f2bf(v.w) << 48);
    *(unsigned long long*)(woutb + (size_t)j * 4) = w;
  } else {
    int k = i - X4 - W4 - O4;      // < 32768
    int ld4 = k * 4;
#pragma unroll
    for (int u = 0; u < 4; u++) {
      int ld = ld4 + u;
      int l = ld >> 6, d = ld & 63;
      cs[ld] = make_float2(cosp[(size_t)l * 128 + d], sinp[(size_t)l * 128 + d]);
    }
  }
}

// ---------------- bf16 GEMM core: C[M,N] = A[M,K] * Bt[N,K]^T, fused epilogues ----------------
// 128x128 tile, BK=32, 4 waves (2x2), wave 64x64 (4x4 MFMA). m97 staging via gload16,
// unpadded LDS rows + chunk XOR swizzle -> 2-way bank alias only (free, m136).
enum { M_F32OUT = 0, M_ROPE = 1, M_VT = 2 };

template <int MODE>
DEVFN void gemm_core(const u16* __restrict__ A, const u16* __restrict__ Bt,
                     void* __restrict__ Cv, const float2* __restrict__ cs,
                     int N, int K, int m0, int n0, u16* As, u16* Bs) {
  int tid = threadIdx.x;
  int wv = tid >> 6, lane = tid & 63, quad = lane >> 4, l16 = lane & 15;
  int wm = (wv >> 1) * 64, wn = (wv & 1) * 64;
  f32x4 acc[4][4] = {};
  int r0 = wv * 16 + (lane >> 2);
  int r1 = r0 + 64;
  int c0 = (lane & 3) ^ ((r0 >> 1) & 3);
  int c1 = (lane & 3) ^ ((r1 >> 1) & 3);
  const u16* Ap0 = A + (size_t)(m0 + r0) * K + c0 * 8;
  const u16* Ap1 = A + (size_t)(m0 + r1) * K + c1 * 8;
  const u16* Bp0 = Bt + (size_t)(n0 + r0) * K + c0 * 8;
  const u16* Bp1 = Bt + (size_t)(n0 + r1) * K + c1 * 8;
  u16* As0 = &As[(wv * 16) * 32];
  u16* As1 = &As[(wv * 16 + 64) * 32];
  u16* Bs0 = &Bs[(wv * 16) * 32];
  u16* Bs1 = &Bs[(wv * 16 + 64) * 32];
  for (int k0 = 0; k0 < K; k0 += 32) {
    __syncthreads();
    gload16(Ap0, As0);
    gload16(Ap1, As1);
    gload16(Bp0, Bs0);
    gload16(Bp1, Bs1);
    Ap0 += 32; Ap1 += 32; Bp0 += 32; Bp1 += 32;
    __syncthreads();
    bf16x8 af[4], bf[4];
#pragma unroll
    for (int i = 0; i < 4; i++) {
      int r = wm + i * 16 + l16;
      af[i] = *(const bf16x8*)&As[r * 32 + ((quad ^ ((r >> 1) & 3)) << 3)];
    }
#pragma unroll
    for (int j = 0; j < 4; j++) {
      int r = wn + j * 16 + l16;
      bf[j] = *(const bf16x8*)&Bs[r * 32 + ((quad ^ ((r >> 1) & 3)) << 3)];
    }
#pragma unroll
    for (int i = 0; i < 4; i++)
#pragma unroll
      for (int j = 0; j < 4; j++) {
        if (MODE == M_VT)
          acc[i][j] = __builtin_amdgcn_mfma_f32_16x16x32_bf16(bf[j], af[i], acc[i][j], 0, 0, 0);
        else
          acc[i][j] = __builtin_amdgcn_mfma_f32_16x16x32_bf16(af[i], bf[j], acc[i][j], 0, 0, 0);
      }
  }
  // C/D layout: col = lane&15, row = quad*4 + reg  (m89/m91 verified)
  if (MODE == M_F32OUT) {
    float* C = (float*)Cv;
#pragma unroll
    for (int i = 0; i < 4; i++)
#pragma unroll
      for (int r = 0; r < 4; r++) {
        size_t row = (size_t)(m0 + wm + i * 16 + quad * 4 + r);
#pragma unroll
        for (int j = 0; j < 4; j++)
          C[row * N + (n0 + wn + j * 16 + l16)] = acc[i][j][r];
      }
  } else if (MODE == M_ROPE) {
    constexpr float QSCALE = 1.4426950408889634f * 0.08838834764831845f;
    const float scale = (n0 >> 11) ? 1.0f : QSCALE;   // q gets log2e/sqrt(128)
    u16* C = (u16*)Cv;
#pragma unroll
    for (int i = 0; i < 4; i++)
#pragma unroll
      for (int r = 0; r < 4; r++) {
        int row = m0 + wm + i * 16 + quad * 4 + r;
        int l = row & 2047;
#pragma unroll
        for (int j = 0; j < 4; j++) {
          int col = n0 + wn + j * 16 + l16;
          int dm = (col & 127) >> 1;
          float2 csv = cs[l * 64 + dm];
          float v = acc[i][j][r];
          float pv = __shfl_xor(v, 1);                 // partner lane (col^1)
          float sg = (l16 & 1) ? csv.y : -csv.y;       // even: -sin, odd: +sin
          C[(size_t)row * 4096 + col] = f2bf((v * csv.x + pv * sg) * scale);
        }
      }
  } else {
    // VT: acc holds C^T tiles; row = v-channel, col = token. Store vt[bh][d][l].
    u16* vt = (u16*)Cv;
#pragma unroll
    for (int j = 0; j < 4; j++)
#pragma unroll
      for (int r = 0; r < 4; r++) {
        int vch = n0 + wn + j * 16 + quad * 4 + r;     // 0..2047
        int h = vch >> 7, d = vch & 127;
#pragma unroll
        for (int i = 0; i < 4; i++) {
          int token = m0 + wm + i * 16 + l16;
          int b = token >> 11, lloc = token & 2047;
          vt[((size_t)(b * 16 + h)) * 262144 + (size_t)d * 2048 + lloc] =
              f2bf(acc[i][j][r]);
        }
      }
  }
}

// Merged QKV GEMM: bx<32 -> RoPE epilogue into qkv (stride 4096); bx>=32 -> V^T.
// 1-D grid with XCD y-striping: each XCD owns an 8-row stripe of M (A rows L2-resident).
__global__ __launch_bounds__(256) void gemm_qkv(const u16* __restrict__ xb,
                                                const u16* __restrict__ wqkvb,
                                                u16* __restrict__ qkvo,
                                                u16* __restrict__ vto,
                                                const float2* __restrict__ cs) {
  __shared__ u16 As[128 * 32];
  __shared__ u16 Bs[128 * 32];
  int id = blockIdx.x;
  int xcd = id & 7, sub = id >> 3;      // sub 0..383
  int bx = sub % 48, by = xcd * 8 + sub / 48;
  if (bx < 32)
    gemm_core<M_ROPE>(xb, wqkvb, qkvo, cs, 0, 2048, by * 128, bx * 128, As, Bs);
  else
    gemm_core<M_VT>(xb, wqkvb + (size_t)4096 * 2048, vto, nullptr, 0, 2048,
                    by * 128, (bx - 32) * 128, As, Bs);
}

__global__ __launch_bounds__(256) void gemm_out_k(const u16* __restrict__ A,
                                                  const u16* __restrict__ Bt,
                                                  float* __restrict__ C) {
  __shared__ u16 As[128 * 32];
  __shared__ u16 Bs[128 * 32];
  int id = blockIdx.x;
  int xcd = id & 7, sub = id >> 3;      // sub 0..127
  int bx = sub % 16, by = xcd * 8 + sub / 16;
  gemm_core<M_F32OUT>(A, Bt, C, nullptr, 2048, 2048, by * 128, bx * 128, As, Bs);
}

// ---------------- fused flash attention (fixed-base softmax) ----------------
// 256 thr = 4 waves; each wave owns 32 Q-rows (2 MFMA bands) -> each K/V LDS fragment
// feeds 2 MFMAs (halves LDS read traffic vs 8x16 layout; LDS-BW was the R3 bottleneck).
// XCD swizzle: all 16 qtiles of one bh on one XCD -> K/V L2-resident.
// LDS rows = 256B, chunk XOR swizzle -> 2-way bank alias (free). 64 KB -> 2 blocks/CU.
DEVFN int swz(int row, int chunk) { return row * 128 + ((chunk ^ (row & 15)) << 3); }

__global__ __launch_bounds__(256, 2) void attn_fused(const u16* __restrict__ qkv,
                                                     const u16* __restrict__ vt,
                                                     u16* __restrict__ out) {
  __shared__ u16 Ksm[128 * 128];
  __shared__ u16 Vsm[128 * 128];
  int tid = threadIdx.x;
  int wv = tid >> 6, lane = tid & 63, quad = lane >> 4, l16 = lane & 15;
  int id = blockIdx.x;
  int xcd = id & 7, sub = id >> 3;             // sub 0..127
  int bh = ((sub >> 4) << 3) | xcd;            // 0..63 : 8 bh per XCD, all 16 qtiles local
  int qt = sub & 15;
  int b = bh >> 4, h = bh & 15;
  const u16* qptr = qkv + (size_t)b * 2048 * 4096 + h * 128;
  const u16* kptr = qptr + 2048;
  const u16* vptr = vt + (size_t)bh * 262144;
  int q0 = qt * 128;
  int rofs = lane >> 4;      // 0..3
  int scc = lane & 15;       // LDS slot-chunk

  // stage Q through Ksm (32 rows/wave)
#pragma unroll
  for (int j = 0; j < 8; j++) {
    int rb = wv * 4 + j * 16;
    int r = rb + rofs;
    int ck = scc ^ (r & 15);
    gload16(&qptr[(size_t)(q0 + r) * 4096 + ck * 8], &Ksm[rb * 128]);
  }
  __syncthreads();
  bf16x8 qf[2][4];
#pragma unroll
  for (int b2 = 0; b2 < 2; b2++)
#pragma unroll
    for (int ks = 0; ks < 4; ks++)
      qf[b2][ks] = *(const bf16x8*)&Ksm[swz(wv * 32 + b2 * 16 + l16, ks * 4 + quad)];

  f32x4 o[2][8] = {};
  float l[2][4] = {};

  for (int kt = 0; kt < 16; kt++) {
    __syncthreads();                       // prior-iteration LDS reads drained
    int kk0 = kt * 128;
#pragma unroll
    for (int j = 0; j < 8; j++) {
      int rb = wv * 4 + j * 16;
      int r = rb + rofs;
      int ck = scc ^ (r & 15);
      gload16(&kptr[(size_t)(kk0 + r) * 4096 + ck * 8], &Ksm[rb * 128]);
      gload16(&vptr[(size_t)r * 2048 + kk0 + ck * 8], &Vsm[rb * 128]);
    }
    __syncthreads();
    // S = Q K^T : read each K fragment once, use for both bands
    f32x4 s[2][8] = {};
#pragma unroll
    for (int ks = 0; ks < 4; ks++)
#pragma unroll
      for (int nt = 0; nt < 8; nt++) {
        bf16x8 bfr = *(const bf16x8*)&Ksm[swz(nt * 16 + l16, ks * 4 + quad)];
        s[0][nt] = __builtin_amdgcn_mfma_f32_16x16x32_bf16(qf[0][ks], bfr, s[0][nt], 0, 0, 0);
        s[1][nt] = __builtin_amdgcn_mfma_f32_16x16x32_bf16(qf[1][ks], bfr, s[1][nt], 0, 0, 0);
      }
    // fixed-base softmax: p = exp2(s); lane-local row sums
#pragma unroll
    for (int b2 = 0; b2 < 2; b2++)
#pragma unroll
      for (int nt = 0; nt < 8; nt++)
#pragma unroll
        for (int r = 0; r < 4; r++) {
          float p = exp2f(s[b2][nt][r]);
          s[b2][nt][r] = p;
          l[b2][r] += p;
        }
    __syncthreads();                       // all waves done reading K from Ksm
    // P (C-layout) -> Ksm in A-layout position; pack col pairs -> b32, even lanes write
#pragma unroll
    for (int b2 = 0; b2 < 2; b2++)
#pragma unroll
      for (int nt = 0; nt < 8; nt++) {
        int col = nt * 16 + l16;
#pragma unroll
        for (int r = 0; r < 4; r++) {
          int row = wv * 32 + b2 * 16 + quad * 4 + r;
          unsigned hw = f2bf(s[b2][nt][r]);
          unsigned hp = (unsigned)__shfl_xor((int)hw, 1);
          if (!(l16 & 1))
            *(unsigned*)&Ksm[swz(row, col >> 3) + (col & 7)] = hw | (hp << 16);
        }
      }
    // O += P V : read each V fragment once, both bands (P rows wave-private, no barrier)
#pragma unroll
    for (int ks = 0; ks < 4; ks++) {
      bf16x8 pf0 = *(const bf16x8*)&Ksm[swz(wv * 32 + l16, ks * 4 + quad)];
      bf16x8 pf1 = *(const bf16x8*)&Ksm[swz(wv * 32 + 16 + l16, ks * 4 + quad)];
#pragma unroll
      for (int nt = 0; nt < 8; nt++) {
        bf16x8 vf = *(const bf16x8*)&Vsm[swz(nt * 16 + l16, ks * 4 + quad)];
        o[0][nt] = __builtin_amdgcn_mfma_f32_16x16x32_bf16(pf0, vf, o[0][nt], 0, 0, 0);
        o[1][nt] = __builtin_amdgcn_mfma_f32_16x16x32_bf16(pf1, vf, o[1][nt], 0, 0, 0);
      }
    }
  }
  // epilogue: reduce l over the 16 col-lanes, divide, pack pairs, store b32
#pragma unroll
  for (int b2 = 0; b2 < 2; b2++)
#pragma unroll
    for (int r = 0; r < 4; r++)
#pragma unroll
      for (int off = 1; off < 16; off <<= 1)
        l[b2][r] += __shfl_xor(l[b2][r], off, 16);
  u16* obase = out + ((size_t)b * 2048 + q0) * 2048 + h * 128;
#pragma unroll
  for (int b2 = 0; b2 < 2; b2++)
#pragma unroll
    for (int r = 0; r < 4; r++) {
      float inv = 1.0f / l[b2][r];
      int row = wv * 32 + b2 * 16 + quad * 4 + r;
#pragma unroll
      for (int nt = 0; nt < 8; nt++) {
        unsigned hw = f2bf(o[b2][nt][r] * inv);
        unsigned hp = (unsigned)__shfl_xor((int)hw, 1);
        if (!(l16 & 1))
          *(unsigned*)&obase[(size_t)row * 2048 + nt * 16 + l16] = hw | (hp << 16);
      }
    }
}

// ---------------- launch ----------------
extern "C" void kernel_launch(void* const* d_in, const int* in_sizes, int n_in,
                              void* d_out, int out_size, void* d_ws, size_t ws_size,
                              hipStream_t stream) {
  const float* x    = (const float*)d_in[0];   // [4,2048,2048]
  const float* cosp = (const float*)d_in[1];   // [2048,128]
  const float* sinp = (const float*)d_in[2];   // [2048,128]
  const float* wqkv = (const float*)d_in[3];   // [6144,2048]
  const float* wout = (const float*)d_in[4];   // [2048,2048]
  float* outp = (float*)d_out;                 // [4,2048,2048] fp32

  u16* ws    = (u16*)d_ws;
  u16* xb    = ws;                     // 16,777,216 elems (dead after GEMM1; reused as attn buf)
  u16* wqkvb = xb + 16777216;          // 12,582,912 (row-permuted q/k)
  u16* woutb = wqkvb + 12582912;       //  4,194,304
  u16* qkv   = woutb + 4194304;        // 33,554,432 (q,k only; row stride 4096)
  u16* vt    = qkv + 33554432;         // 16,777,216
  float2* cs = (float2*)(vt + 16777216); // 131,072 float2 = 1 MB
  u16* attn  = xb;                     // alias: xb dead after gemm_qkv

  prep<<<32896, 256, 0, stream>>>(x, wqkv, wout, cosp, sinp, xb, wqkvb, woutb, cs);
  gemm_qkv<<<3072, 256, 0, stream>>>(xb, wqkvb, qkv, vt, cs);
  attn_fused<<<1024, 256, 0, stream>>>(qkv, vt, attn);
  gemm_out_k<<<1024, 256, 0, stream>>>(attn, woutb, outp);
}

// Round 5
// 725.421 us; speedup vs baseline: 1.5960x; 1.5960x over previous
//
#include <hip/hip_runtime.h>
#include <cstdint>
#include <cstddef>

typedef unsigned short u16;
typedef __attribute__((ext_vector_type(8))) short bf16x8;   // 8 bf16 = 4 VGPRs
typedef __attribute__((ext_vector_type(4))) float f32x4;    // MFMA accumulator

#define DEVFN static __device__ __forceinline__

DEVFN u16 f2bf(float f) {
  unsigned u = __float_as_uint(f);
  unsigned r = (u + 0x7FFFu + ((u >> 16) & 1u)) >> 16;   // RTN-even
  return (u16)r;
}

// async global->LDS, 16B/lane. LDS dest = wave-uniform base + lane*16 (m104/m108).
DEVFN void gload16(const void* g, void* l) {
  __builtin_amdgcn_global_load_lds(
      (const __attribute__((address_space(1))) void*)g,
      (__attribute__((address_space(3))) void*)l, 16, 0, 0);
}

// ---------------- merged prep: converts + wqkv row-permute + cos/sin table ----------------
// wqkv q/k rows interleaved per head: d<64 -> 2d, d>=64 -> 2(d-64)+1  (QK^T invariant).
// cs[l*64+m] = (cos(l,m), sin(l,m))
__global__ void prep(const float* __restrict__ x, const float* __restrict__ wqkv,
                     const float* __restrict__ wout, const float* __restrict__ cosp,
                     const float* __restrict__ sinp, u16* __restrict__ xb,
                     u16* __restrict__ wqkvb, u16* __restrict__ woutb,
                     float2* __restrict__ cs) {
  constexpr int X4 = 4194304;      // x elems/4
  constexpr int W4 = 3145728;      // wqkv elems/4
  constexpr int O4 = 1048576;      // wout elems/4
  int i = blockIdx.x * blockDim.x + threadIdx.x;
  if (i < X4) {
    float4 v = ((const float4*)x)[i];
    unsigned long long w = (unsigned long long)f2bf(v.x)
        | ((unsigned long long)f2bf(v.y) << 16)
        | ((unsigned long long)f2bf(v.z) << 32)
        | ((unsigned long long)f2bf(v.w) << 48);
    *(unsigned long long*)(xb + (size_t)i * 4) = w;
  } else if (i < X4 + W4) {
    int j = i - X4;
    int base = j * 4;
    int e = base >> 11, col = base & 2047;
    int e2;
    if (e < 4096) {
      int part = e >> 11, loc = e & 2047;
      int h = loc >> 7, d = loc & 127;
      int d2 = (d < 64) ? 2 * d : 2 * (d - 64) + 1;
      e2 = part * 2048 + h * 128 + d2;
    } else {
      e2 = e;                      // v rows unpermuted
    }
    float4 v = *(const float4*)&wqkv[(size_t)base];
    unsigned long long w = (unsigned long long)f2bf(v.x)
        | ((unsigned long long)f2bf(v.y) << 16)
        | ((unsigned long long)f2bf(v.z) << 32)
        | ((unsigned long long)f2bf(v.w) << 48);
    *(unsigned long long*)(wqkvb + (size_t)e2 * 2048 + col) = w;
  } else if (i < X4 + W4 + O4) {
    int j = i - X4 - W4;
    float4 v = ((const float4*)wout)[j];
    unsigned long long w = (unsigned long long)f2bf(v.x)
        | ((unsigned long long)f2bf(v.y) << 16)
        | ((unsigned long long)f2bf(v.z) << 32)
        | ((unsigned long long)f2bf(v.w) << 48);
    *(unsigned long long*)(woutb + (size_t)j * 4) = w;
  } else {
    int k = i - X4 - W4 - O4;      // < 32768
    int ld4 = k * 4;
#pragma unroll
    for (int u = 0; u < 4; u++) {
      int ld = ld4 + u;
      int l = ld >> 6, d = ld & 63;
      cs[ld] = make_float2(cosp[(size_t)l * 128 + d], sinp[(size_t)l * 128 + d]);
    }
  }
}

// ---------------- bf16 GEMM core: C[M,N] = A[M,K] * Bt[N,K]^T, fused epilogues ----------------
// 128x128 tile, BK=32, 4 waves (2x2), wave 64x64 (4x4 MFMA). m97 staging via gload16,
// unpadded LDS rows + chunk XOR swizzle -> 2-way bank alias only (free, m136).
enum { M_F32OUT = 0, M_ROPE = 1, M_VT = 2 };

template <int MODE>
DEVFN void gemm_core(const u16* __restrict__ A, const u16* __restrict__ Bt,
                     void* __restrict__ Cv, const float2* __restrict__ cs,
                     int N, int K, int m0, int n0, u16* As, u16* Bs) {
  int tid = threadIdx.x;
  int wv = tid >> 6, lane = tid & 63, quad = lane >> 4, l16 = lane & 15;
  int wm = (wv >> 1) * 64, wn = (wv & 1) * 64;
  f32x4 acc[4][4] = {};
  int r0 = wv * 16 + (lane >> 2);
  int r1 = r0 + 64;
  int c0 = (lane & 3) ^ ((r0 >> 1) & 3);
  int c1 = (lane & 3) ^ ((r1 >> 1) & 3);
  const u16* Ap0 = A + (size_t)(m0 + r0) * K + c0 * 8;
  const u16* Ap1 = A + (size_t)(m0 + r1) * K + c1 * 8;
  const u16* Bp0 = Bt + (size_t)(n0 + r0) * K + c0 * 8;
  const u16* Bp1 = Bt + (size_t)(n0 + r1) * K + c1 * 8;
  u16* As0 = &As[(wv * 16) * 32];
  u16* As1 = &As[(wv * 16 + 64) * 32];
  u16* Bs0 = &Bs[(wv * 16) * 32];
  u16* Bs1 = &Bs[(wv * 16 + 64) * 32];
  for (int k0 = 0; k0 < K; k0 += 32) {
    __syncthreads();
    gload16(Ap0, As0);
    gload16(Ap1, As1);
    gload16(Bp0, Bs0);
    gload16(Bp1, Bs1);
    Ap0 += 32; Ap1 += 32; Bp0 += 32; Bp1 += 32;
    __syncthreads();
    bf16x8 af[4], bf[4];
#pragma unroll
    for (int i = 0; i < 4; i++) {
      int r = wm + i * 16 + l16;
      af[i] = *(const bf16x8*)&As[r * 32 + ((quad ^ ((r >> 1) & 3)) << 3)];
    }
#pragma unroll
    for (int j = 0; j < 4; j++) {
      int r = wn + j * 16 + l16;
      bf[j] = *(const bf16x8*)&Bs[r * 32 + ((quad ^ ((r >> 1) & 3)) << 3)];
    }
#pragma unroll
    for (int i = 0; i < 4; i++)
#pragma unroll
      for (int j = 0; j < 4; j++) {
        if (MODE == M_VT)
          acc[i][j] = __builtin_amdgcn_mfma_f32_16x16x32_bf16(bf[j], af[i], acc[i][j], 0, 0, 0);
        else
          acc[i][j] = __builtin_amdgcn_mfma_f32_16x16x32_bf16(af[i], bf[j], acc[i][j], 0, 0, 0);
      }
  }
  // C/D layout: col = lane&15, row = quad*4 + reg  (m89/m91 verified)
  if (MODE == M_F32OUT) {
    float* C = (float*)Cv;
#pragma unroll
    for (int i = 0; i < 4; i++)
#pragma unroll
      for (int r = 0; r < 4; r++) {
        size_t row = (size_t)(m0 + wm + i * 16 + quad * 4 + r);
#pragma unroll
        for (int j = 0; j < 4; j++)
          C[row * N + (n0 + wn + j * 16 + l16)] = acc[i][j][r];
      }
  } else if (MODE == M_ROPE) {
    constexpr float QSCALE = 1.4426950408889634f * 0.08838834764831845f;
    const float scale = (n0 >> 11) ? 1.0f : QSCALE;   // q gets log2e/sqrt(128)
    u16* C = (u16*)Cv;
#pragma unroll
    for (int i = 0; i < 4; i++)
#pragma unroll
      for (int r = 0; r < 4; r++) {
        int row = m0 + wm + i * 16 + quad * 4 + r;
        int l = row & 2047;
#pragma unroll
        for (int j = 0; j < 4; j++) {
          int col = n0 + wn + j * 16 + l16;
          int dm = (col & 127) >> 1;
          float2 csv = cs[l * 64 + dm];
          float v = acc[i][j][r];
          float pv = __shfl_xor(v, 1);                 // partner lane (col^1)
          float sg = (l16 & 1) ? csv.y : -csv.y;       // even: -sin, odd: +sin
          C[(size_t)row * 4096 + col] = f2bf((v * csv.x + pv * sg) * scale);
        }
      }
  } else {
    // VT: acc holds C^T tiles; row = v-channel, col = token. Store vt[bh][d][l].
    u16* vt = (u16*)Cv;
#pragma unroll
    for (int j = 0; j < 4; j++)
#pragma unroll
      for (int r = 0; r < 4; r++) {
        int vch = n0 + wn + j * 16 + quad * 4 + r;     // 0..2047
        int h = vch >> 7, d = vch & 127;
#pragma unroll
        for (int i = 0; i < 4; i++) {
          int token = m0 + wm + i * 16 + l16;
          int b = token >> 11, lloc = token & 2047;
          vt[((size_t)(b * 16 + h)) * 262144 + (size_t)d * 2048 + lloc] =
              f2bf(acc[i][j][r]);
        }
      }
  }
}

// Merged QKV GEMM: bx<32 -> RoPE epilogue into qkv (stride 4096); bx>=32 -> V^T.
// 1-D grid with XCD y-striping: each XCD owns an 8-row stripe of M (A rows L2-resident).
__global__ __launch_bounds__(256) void gemm_qkv(const u16* __restrict__ xb,
                                                const u16* __restrict__ wqkvb,
                                                u16* __restrict__ qkvo,
                                                u16* __restrict__ vto,
                                                const float2* __restrict__ cs) {
  __shared__ u16 As[128 * 32];
  __shared__ u16 Bs[128 * 32];
  int id = blockIdx.x;
  int xcd = id & 7, sub = id >> 3;      // sub 0..383
  int bx = sub % 48, by = xcd * 8 + sub / 48;
  if (bx < 32)
    gemm_core<M_ROPE>(xb, wqkvb, qkvo, cs, 0, 2048, by * 128, bx * 128, As, Bs);
  else
    gemm_core<M_VT>(xb, wqkvb + (size_t)4096 * 2048, vto, nullptr, 0, 2048,
                    by * 128, (bx - 32) * 128, As, Bs);
}

__global__ __launch_bounds__(256) void gemm_out_k(const u16* __restrict__ A,
                                                  const u16* __restrict__ Bt,
                                                  float* __restrict__ C) {
  __shared__ u16 As[128 * 32];
  __shared__ u16 Bs[128 * 32];
  int id = blockIdx.x;
  int xcd = id & 7, sub = id >> 3;      // sub 0..127
  int bx = sub % 16, by = xcd * 8 + sub / 16;
  gemm_core<M_F32OUT>(A, Bt, C, nullptr, 2048, 2048, by * 128, bx * 128, As, Bs);
}

// ---------------- fused flash attention (fixed-base softmax, no online max) ----------------
// R3-proven structure: 512 thr = 8 waves, 16 Q-rows/wave (108 VGPR, no spill — R4's
// 32-rows/wave variant spilled: 160 acc regs vs 128 budget at 2 blk/CU).
// XCD swizzle: all 16 qtiles of one bh on one XCD -> K/V served from L2.
// LDS rows = 256B, chunk XOR swizzle -> 2-way bank alias (free, m136).
DEVFN int swz(int row, int chunk) { return row * 128 + ((chunk ^ (row & 15)) << 3); }

__global__ __launch_bounds__(512) void attn_fused(const u16* __restrict__ qkv,
                                                  const u16* __restrict__ vt,
                                                  u16* __restrict__ out) {
  __shared__ u16 Ksm[128 * 128];
  __shared__ u16 Vsm[128 * 128];
  int tid = threadIdx.x;
  int wv = tid >> 6, lane = tid & 63, quad = lane >> 4, l16 = lane & 15;
  int id = blockIdx.x;
  int xcd = id & 7, sub = id >> 3;             // sub 0..127
  int bh = ((sub >> 4) << 3) | xcd;            // 8 bh per XCD, all 16 qtiles local
  int qt = sub & 15;
  int b = bh >> 4, h = bh & 15;
  const u16* qptr = qkv + (size_t)b * 2048 * 4096 + h * 128;
  const u16* kptr = qptr + 2048;
  const u16* vptr = vt + (size_t)bh * 262144;
  int q0 = qt * 128;

  int rofs = lane >> 4;      // 0..3 (row within a 4-row gload group)
  int scc = lane & 15;       // LDS slot-chunk

  // stage Q through Ksm via global_load_lds, pull A-fragments to registers
#pragma unroll
  for (int j = 0; j < 4; j++) {
    int rb = wv * 4 + j * 32;
    int r = rb + rofs;
    int ck = scc ^ (r & 15);
    gload16(&qptr[(size_t)(q0 + r) * 4096 + ck * 8], &Ksm[rb * 128]);
  }
  __syncthreads();
  bf16x8 qf[4];
#pragma unroll
  for (int ks = 0; ks < 4; ks++)
    qf[ks] = *(const bf16x8*)&Ksm[swz(wv * 16 + l16, ks * 4 + quad)];

  f32x4 o[8] = {};
  float l[4] = {0.f, 0.f, 0.f, 0.f};

  for (int kt = 0; kt < 16; kt++) {
    __syncthreads();                       // prior-iteration LDS reads drained
    int kk0 = kt * 128;
#pragma unroll
    for (int j = 0; j < 4; j++) {
      int rb = wv * 4 + j * 32;
      int r = rb + rofs;
      int ck = scc ^ (r & 15);
      gload16(&kptr[(size_t)(kk0 + r) * 4096 + ck * 8], &Ksm[rb * 128]);
      gload16(&vptr[(size_t)r * 2048 + kk0 + ck * 8], &Vsm[rb * 128]);
    }
    __syncthreads();
    // S = Q K^T (scores already in log2 domain via QSCALE folded into q)
    f32x4 s[8] = {};
#pragma unroll
    for (int ks = 0; ks < 4; ks++) {
      bf16x8 bfr[8];
#pragma unroll
      for (int nt = 0; nt < 8; nt++)
        bfr[nt] = *(const bf16x8*)&Ksm[swz(nt * 16 + l16, ks * 4 + quad)];
#pragma unroll
      for (int nt = 0; nt < 8; nt++)
        s[nt] = __builtin_amdgcn_mfma_f32_16x16x32_bf16(qf[ks], bfr[nt], s[nt], 0, 0, 0);
    }
    // fixed-base softmax: p = exp2(s); lane-local row-sum accumulation only
#pragma unroll
    for (int nt = 0; nt < 8; nt++)
#pragma unroll
      for (int r = 0; r < 4; r++) {
        float p = exp2f(s[nt][r]);
        s[nt][r] = p;
        l[r] += p;
      }
    __syncthreads();                       // all waves done reading K from Ksm
    // P (C-layout) -> Ksm in A-operand layout position (same-wave rows; no extra barrier)
#pragma unroll
    for (int nt = 0; nt < 8; nt++)
#pragma unroll
      for (int r = 0; r < 4; r++) {
        int row = wv * 16 + quad * 4 + r;
        int col = nt * 16 + l16;
        Ksm[swz(row, col >> 3) + (col & 7)] = f2bf(s[nt][r]);
      }
    // O += P V  (Vsm holds V^T per head: rows = d, cols = keys)
#pragma unroll
    for (int ks = 0; ks < 4; ks++) {
      bf16x8 pf = *(const bf16x8*)&Ksm[swz(wv * 16 + l16, ks * 4 + quad)];
#pragma unroll
      for (int nt = 0; nt < 8; nt++) {
        bf16x8 vf = *(const bf16x8*)&Vsm[swz(nt * 16 + l16, ks * 4 + quad)];
        o[nt] = __builtin_amdgcn_mfma_f32_16x16x32_bf16(pf, vf, o[nt], 0, 0, 0);
      }
    }
  }
  // epilogue: reduce l across the 16 col-lanes once, divide, store bf16
#pragma unroll
  for (int r = 0; r < 4; r++)
#pragma unroll
    for (int off = 1; off < 16; off <<= 1) l[r] += __shfl_xor(l[r], off, 16);
  u16* obase = out + ((size_t)b * 2048 + q0) * 2048 + h * 128;
#pragma unroll
  for (int r = 0; r < 4; r++) {
    float inv = 1.0f / l[r];
    int row = wv * 16 + quad * 4 + r;
#pragma unroll
    for (int nt = 0; nt < 8; nt++)
      obase[(size_t)row * 2048 + nt * 16 + l16] = f2bf(o[nt][r] * inv);
  }
}

// ---------------- launch ----------------
extern "C" void kernel_launch(void* const* d_in, const int* in_sizes, int n_in,
                              void* d_out, int out_size, void* d_ws, size_t ws_size,
                              hipStream_t stream) {
  const float* x    = (const float*)d_in[0];   // [4,2048,2048]
  const float* cosp = (const float*)d_in[1];   // [2048,128]
  const float* sinp = (const float*)d_in[2];   // [2048,128]
  const float* wqkv = (const float*)d_in[3];   // [6144,2048]
  const float* wout = (const float*)d_in[4];   // [2048,2048]
  float* outp = (float*)d_out;                 // [4,2048,2048] fp32

  u16* ws    = (u16*)d_ws;
  u16* xb    = ws;                     // 16,777,216 elems (dead after gemm_qkv; reused)
  u16* wqkvb = xb + 16777216;          // 12,582,912 (row-permuted q/k)
  u16* woutb = wqkvb + 12582912;       //  4,194,304
  u16* qkv   = woutb + 4194304;        // 33,554,432 (q,k only; row stride 4096)
  u16* vt    = qkv + 33554432;         // 16,777,216
  float2* cs = (float2*)(vt + 16777216); // 131,072 float2 = 1 MB
  u16* attn  = xb;                     // alias: xb dead after gemm_qkv

  prep<<<32896, 256, 0, stream>>>(x, wqkv, wout, cosp, sinp, xb, wqkvb, woutb, cs);
  gemm_qkv<<<3072, 256, 0, stream>>>(xb, wqkvb, qkv, vt, cs);
  attn_fused<<<1024, 512, 0, stream>>>(qkv, vt, attn);
  gemm_out_k<<<1024, 256, 0, stream>>>(attn, woutb, outp);
}